// Round 15
// baseline (31.670 us; speedup 1.0000x reference)
//
#include <hip/hip_runtime.h>

// RFCN PSROI — 2-launch pipeline (r14 skeleton, wfold fused into proj):
//   out[b,n,g] = B'[g] + (1/denom) * sum_{bin} Z[b,g,h,w]
//   Z = einsum('bchw,gc->bghw', features, W'),  W'[g,c] = sum_k w[g*9+k, c]
// K1: per-block fold of THIS chunk's 25x256 weight slice into LDS (230 KB
//     L2-served reads, redundant across the 128 blocks sharing a chunk),
//     then projection -> 25-ch partial maps. 51.2 KB LDS -> 2+ blocks/CU so
//     one block's fold overlaps another's FMA phase (r13 failed at 1 blk/CU).
// K2: per (b,g): inline bias + 4-chunk sum + 2D prefix scan + gather.
// No cross-block sync anywhere (r10: 261us, r12: 174us on 8 XCDs).

#define HW 4096      // 64*64
#define NG 25        // 21 cls + 4 reg groups
#define CIN 1024
#define B 2
#define NPROP 1000
#define NCH 4                 // channel chunks in workspace
#define CK (CIN / NCH)        // 256 channels per chunk
#define NSL 8                 // waves per proj block
#define CS (CK / NSL)         // 32 channels per wave
#define MHW (B * NG * HW)     // 204800: one partial chunk

// ---------------- Kernel 1: in-LDS chunk fold + projection ----------------
// grid = (64 px tiles, 4 chunks, B) = 512 blocks, block = 512 (8 waves).
// LDS: wlds 25.6 KB + red 25.6 KB = 51.2 KB -> 2+ blocks/CU.
// part layout: [chunk][b][g][4096]
__global__ __launch_bounds__(512)
void rfcn_projf(const float* __restrict__ feats,
                const float* __restrict__ w_cls,
                const float* __restrict__ w_reg,
                float* __restrict__ part) {
    const int t = threadIdx.x;
    const int chunk = blockIdx.y;
    const int b = blockIdx.z;
    __shared__ float wlds[NG * CK];           // 25.6 KB folded chunk weights
    __shared__ float red[(NSL / 2) * NG * 64]; // 25.6 KB reduce buffer

    // ---- phase A: fold this chunk's 25x256 slice (L2/L3-served reads) ----
    for (int idx = t; idx < NG * CK; idx += 512) {
        const int g = idx >> 8;                  // /CK
        const int c = idx & (CK - 1);
        const int gc = chunk * CK + c;           // global channel
        float s = 0.f;
        if (g < 21) {
            #pragma unroll
            for (int k = 0; k < 9; ++k) s += w_cls[(size_t)(g * 9 + k) * CIN + gc];
        } else {
            const int gr = g - 21;
            #pragma unroll
            for (int k = 0; k < 9; ++k) s += w_reg[(size_t)(gr * 9 + k) * CIN + gc];
        }
        wlds[idx] = s;
    }
    __syncthreads();

    // ---- phase B: projection (r14 body; weights via LDS broadcast) -------
    const int p = t & 63;                       // pixel within tile
    const int sl = __builtin_amdgcn_readfirstlane(t >> 6);   // 0..7 (SGPR)
    const int pix0 = blockIdx.x * 64;
    const int c0 = chunk * CK + sl * CS;        // wave's first channel

    const float* __restrict__ f = feats + ((size_t)b * CIN + c0) * HW + pix0 + p;
    // wave's folded-weight slice: uniform addr -> broadcast ds_read_b128
    const float4* __restrict__ w4 = (const float4*)(wlds + sl * CS);

    float acc[NG];
    #pragma unroll
    for (int g = 0; g < NG; ++g) acc[g] = 0.f;

    // all 32 channel loads independent and in flight
    float fv[CS];
    #pragma unroll
    for (int j = 0; j < CS; ++j) fv[j] = f[(size_t)j * HW];

    #pragma unroll
    for (int g = 0; g < NG; ++g) {
        float a = 0.f;
        #pragma unroll
        for (int q = 0; q < CS / 4; ++q) {      // 8 x ds_read_b128
            const float4 w = w4[(size_t)g * (CK / 4) + q];
            a += fv[4 * q]     * w.x;
            a += fv[4 * q + 1] * w.y;
            a += fv[4 * q + 2] * w.z;
            a += fv[4 * q + 3] * w.w;
        }
        acc[g] = a;
    }

    // paired-wave LDS reduction: red[4][25][64]
    if (sl >= 4) {
        #pragma unroll
        for (int g = 0; g < NG; ++g) red[((sl - 4) * NG + g) * 64 + p] = acc[g];
    }
    __syncthreads();
    if (sl < 4) {
        #pragma unroll
        for (int g = 0; g < NG; ++g) red[(sl * NG + g) * 64 + p] += acc[g];
    }
    __syncthreads();

    // 4->1 sum + coalesced store
    float* __restrict__ o = part + ((size_t)(chunk * B + b) * NG) * HW + pix0;
    for (int idx = t; idx < NG * 64; idx += 512) {
        const int g = idx >> 6, pp = idx & 63;
        float s = red[(0 * NG + g) * 64 + pp] + red[(1 * NG + g) * 64 + pp]
                + red[(2 * NG + g) * 64 + pp] + red[(3 * NG + g) * 64 + pp];
        o[(size_t)g * HW + pp] = s;
    }
}

// ---------------- Kernel 2: bias + 4-chunk sum + prefix scan + gather ------
// grid = 50 (m = b*25+g), block = 1024 (16 waves); each wave scans 4 rows
// then 4 cols (independent 6-deep shfl chains).
// LDS 64x65: pad kills row-phase conflicts; col stride 65 == 1 (mod 32).
__global__ __launch_bounds__(1024)
void rfcn_ig(const float* __restrict__ part,
             const int* __restrict__ props,
             const float* __restrict__ b_cls,
             const float* __restrict__ b_reg,
             float* __restrict__ out) {
    const int m = blockIdx.x;        // b*25 + g
    const int t = threadIdx.x;
    const int lane = t & 63;
    const int wave = t >> 6;         // 0..15
    const int b = m / NG;
    const int g = m - b * NG;        // block-uniform
    __shared__ float tile[64 * 65];

    // inline bias fold (block-uniform g -> scalar s_loads)
    float bias = 0.f;
    if (g < 21) {
        #pragma unroll
        for (int k = 0; k < 9; ++k) bias += b_cls[g * 9 + k];
    } else {
        #pragma unroll
        for (int k = 0; k < 9; ++k) bias += b_reg[(g - 21) * 9 + k];
    }

    // phase 1: sum the 4 partial chunks (16 independent coalesced loads)
    #pragma unroll
    for (int i = 0; i < 4; ++i) {
        const int idx = i * 1024 + t;
        float v[NCH];
        #pragma unroll
        for (int ch = 0; ch < NCH; ++ch)
            v[ch] = part[(size_t)(ch * (B * NG) + m) * HW + idx];
        #pragma unroll
        for (int off = NCH / 2; off >= 1; off >>= 1)
            #pragma unroll
            for (int j = 0; j < off; ++j) v[j] += v[j + off];
        tile[(idx >> 6) * 65 + (idx & 63)] = v[0];
    }
    __syncthreads();

    // phase 2: row scans — wave w owns rows [w*4, w*4+4), lane = column
    #pragma unroll
    for (int i = 0; i < 4; ++i) {
        const int row = wave * 4 + i;
        float v = tile[row * 65 + lane];
        #pragma unroll
        for (int d = 1; d < 64; d <<= 1) {
            float u = __shfl_up(v, (unsigned)d, 64);
            if (lane >= d) v += u;
        }
        tile[row * 65 + lane] = v;
    }
    __syncthreads();

    // phase 3: column scans — wave w owns cols [w*4, w*4+4), lane = row
    #pragma unroll
    for (int i = 0; i < 4; ++i) {
        const int col = wave * 4 + i;
        float v = tile[lane * 65 + col];
        #pragma unroll
        for (int d = 1; d < 64; d <<= 1) {
            float u = __shfl_up(v, (unsigned)d, 64);
            if (lane >= d) v += u;
        }
        tile[lane * 65 + col] = v;
    }
    __syncthreads();

    // phase 4: per-proposal 4-corner lookups straight from LDS
    const int n = t;
    if (n < NPROP) {
        const int4 pr = ((const int4*)props)[b * NPROP + n];
        const int x1 = pr.x >> 5;            // floor(px/32), px >= 0
        const int y1 = pr.y >> 5;
        const int x2 = (pr.z + 31) >> 5;     // ceil
        const int y2 = (pr.w + 31) >> 5;
        const int wb = (x2 - x1 + 2) / 3;    // ceil((x2-x1)/3), >= 1
        const int hb = (y2 - y1 + 2) / 3;
        const int c2 = x1 + wb - 1;          // inclusive corner, <= 63
        const int r2 = y1 + hb - 1;

        float s = tile[r2 * 65 + c2];
        if (x1 > 0)           s -= tile[r2 * 65 + (x1 - 1)];
        if (y1 > 0)           s -= tile[(y1 - 1) * 65 + c2];
        if (x1 > 0 && y1 > 0) s += tile[(y1 - 1) * 65 + (x1 - 1)];
        const float v = bias + s / (float)(hb * wb);
        if (g < 21)  // block-uniform branch
            out[(size_t)(b * NPROP + n) * 21 + g] = v;
        else
            out[(size_t)(B * NPROP * 21) + (size_t)(b * NPROP + n) * 4 + (g - 21)] = v;
    }
}

extern "C" void kernel_launch(void* const* d_in, const int* in_sizes, int n_in,
                              void* d_out, int out_size, void* d_ws, size_t ws_size,
                              hipStream_t stream) {
    const float* feats = (const float*)d_in[0];  // [2,1024,64,64]
    const float* w_cls = (const float*)d_in[1];  // [189,1024]
    const float* b_cls = (const float*)d_in[2];  // [189]
    const float* w_reg = (const float*)d_in[3];  // [36,1024]
    const float* b_reg = (const float*)d_in[4];  // [36]
    const int*   props = (const int*)d_in[5];    // [2,1000,4]
    float* out = (float*)d_out;
    float* ws  = (float*)d_ws;

    float* part = ws;                            // 4 * 204800 floats (3.3 MB)

    rfcn_projf<<<dim3(HW / 64, NCH, B), 512, 0, stream>>>(
        feats, w_cls, w_reg, part);
    rfcn_ig<<<B * NG, 1024, 0, stream>>>(part, props, b_cls, b_reg, out);
}